// Round 6
// baseline (428.064 us; speedup 1.0000x reference)
//
#include <hip/hip_runtime.h>

// db2 analysis filters (already reversed per pytorch_wavelets.prep_filt_afb1d)
#define H00  0.48296291314469025f
#define H01  0.8365163037378079f
#define H02  0.22414386804185735f
#define H03 -0.12940952255092145f

#define H10 -0.12940952255092145f
#define H11 -0.22414386804185735f
#define H12  0.8365163037378079f
#define H13 -0.48296291314469025f

typedef float f4 __attribute__((ext_vector_type(4)));

namespace {
constexpr int Bn      = 16;
constexpr int Cn      = 256;
constexpr int PLANE4  = (128 * 128) / 4;   // 4096 f4 per channel plane (64 KiB)
constexpr int KPC     = 8;                 // output (lo,hi) pairs per block
constexpr int CHUNKS  = (Cn / 2) / KPC;    // 16 chunks per batch
constexpr int THREADS = 1024;              // one block covers a whole plane
constexpr int JPT     = PLANE4 / THREADS;  // 4 f4 slots per thread per plane
}  // namespace

// Each block owns (b, k0..k0+7). It streams CONTIGUOUS memory:
//   reads planes 2k0-2 .. 2k0+15 in ascending address order (1.125 MiB),
//   writes lo planes k0..k0+7 and hi planes 128+k0..128+k0+7 (two sequential
//   streams). This keeps per-HBM-channel request streams sequential (DRAM row
//   locality) instead of the 64 KiB-strided column walk that ran at 1.3 TB/s.
__global__ __launch_bounds__(THREADS, 4) void dwt_db2_channel_kernel(
    const f4* __restrict__ x, f4* __restrict__ out)
{
    const unsigned blk   = blockIdx.x;
    const unsigned b     = blk >> 4;        // 16 chunks per batch
    const unsigned chunk = blk & 15u;
    const int      k0    = chunk * KPC;
    const unsigned t     = threadIdx.x;

    const f4* __restrict__ xp  = x   + (size_t)b * Cn * PLANE4
                                     + (size_t)(2 * k0) * PLANE4 + t;
    f4*       __restrict__ plo = out + (size_t)b * Cn * PLANE4
                                     + (size_t)k0 * PLANE4 + t;
    f4*       __restrict__ phi = plo + (size_t)(Cn / 2) * PLANE4;

    // sliding window: w0,w1 = planes 2k-2, 2k-1 (this thread's 4 slots each)
    f4 w0[JPT], w1[JPT];
    if (chunk == 0) {
        // zero-mode padding: channels -2, -1 are zero
#pragma unroll
        for (int j = 0; j < JPT; ++j) {
            w0[j] = (f4){0.f, 0.f, 0.f, 0.f};
            w1[j] = (f4){0.f, 0.f, 0.f, 0.f};
        }
    } else {
#pragma unroll
        for (int j = 0; j < JPT; ++j)
            w0[j] = __builtin_nontemporal_load(xp - 2 * PLANE4 + j * THREADS);
#pragma unroll
        for (int j = 0; j < JPT; ++j)
            w1[j] = __builtin_nontemporal_load(xp - 1 * PLANE4 + j * THREADS);
    }

#pragma unroll 1
    for (int kk = 0; kk < KPC; ++kk) {
        f4 w2[JPT], w3[JPT];
#pragma unroll
        for (int j = 0; j < JPT; ++j)
            w2[j] = __builtin_nontemporal_load(xp + j * THREADS);
#pragma unroll
        for (int j = 0; j < JPT; ++j)
            w3[j] = __builtin_nontemporal_load(xp + PLANE4 + j * THREADS);
        xp += 2 * PLANE4;

#pragma unroll
        for (int j = 0; j < JPT; ++j) {
            const f4 lo = H00 * w0[j] + H01 * w1[j] + H02 * w2[j] + H03 * w3[j];
            const f4 hi = H10 * w0[j] + H11 * w1[j] + H12 * w2[j] + H13 * w3[j];
            __builtin_nontemporal_store(lo, plo + j * THREADS);
            __builtin_nontemporal_store(hi, phi + j * THREADS);
            w0[j] = w2[j];
            w1[j] = w3[j];
        }
        plo += PLANE4;
        phi += PLANE4;
    }
}

extern "C" void kernel_launch(void* const* d_in, const int* in_sizes, int n_in,
                              void* d_out, int out_size, void* d_ws, size_t ws_size,
                              hipStream_t stream) {
    (void)in_sizes; (void)n_in; (void)d_ws; (void)ws_size; (void)out_size;
    const f4* x   = (const f4*)d_in[0];
    f4*       out = (f4*)d_out;

    const unsigned grid = Bn * CHUNKS;  // 256 blocks, one per CU
    dwt_db2_channel_kernel<<<grid, THREADS, 0, stream>>>(x, out);
}